// Round 6
// baseline (697.483 us; speedup 1.0000x reference)
//
#include <hip/hip_runtime.h>
#include <hip/hip_cooperative_groups.h>

namespace cg = cooperative_groups;

#define N_NODES 40000
#define N_EDGES 640000
#define NGRAPH 64
#define NBCH 157   // (N_NODES+255)/256

typedef unsigned short u16;
typedef unsigned int u32;
typedef __attribute__((ext_vector_type(4))) float floatx4;
typedef __attribute__((ext_vector_type(8))) short short8;
typedef __attribute__((ext_vector_type(8))) __bf16 bf16x8;

__device__ __forceinline__ float bf2f(u16 u) {
  u32 x = ((u32)u) << 16;
  return __builtin_bit_cast(float, x);
}
__device__ __forceinline__ u16 f2bf(float f) {
  u32 u = __builtin_bit_cast(u32, f);
  u += 0x7fffu + ((u >> 16) & 1u);   // RNE
  return (u16)(u >> 16);
}
__device__ __forceinline__ uint2 f4tob(float4 v) {
  u32 lo = (u32)f2bf(v.x) | ((u32)f2bf(v.y) << 16);
  u32 hi = (u32)f2bf(v.z) | ((u32)f2bf(v.w) << 16);
  return make_uint2(lo, hi);
}
__device__ __forceinline__ void gld16(const void* g, void* l) {
  __builtin_amdgcn_global_load_lds(
      (const __attribute__((address_space(1))) u32*)g,
      (__attribute__((address_space(3))) u32*)l, 16, 0, 0);
}

// ================= cooperative PRE kernel: zero + f2b + CSR build =================
struct PreArgs {
  const float* x_bb;
  const float *W1l, *W1r, *W2l, *W2r, *W3l, *W3r;
  const int* ei;
  const int* batch;
  u16 *xb, *w1l, *w1r, *w2l, *w2r, *w3s, *w3r;
  int* cnt;      // cnt[N] | cursor[N] | gsum[8192 f32] contiguous (zeroed together)
  int* cursor;
  int* rowptr;   // [N+1]
  float* invc;
  int* bsum;
  int* gstart;
  int* perm;
};

__global__ __launch_bounds__(256, 4) void k_pre(PreArgs a) {
  cg::grid_group grid = cg::this_grid();
  __shared__ int ssc[256];
  const int t = threadIdx.x;
  const int tid = blockIdx.x * 256 + t;
  const int nth = gridDim.x * 256;

  // P0a: zero cnt|cursor|gsum
  for (int i = tid; i < 2 * N_NODES + 8192; i += nth) a.cnt[i] = 0;
  // P0b: x_bb -> bf16
  for (int i = tid; i < N_NODES * 32; i += nth)
    ((uint2*)a.xb)[i] = f4tob(((const float4*)a.x_bb)[i]);
  // P0c: all six weight matrices -> bf16 (65536 float4s)
  for (int i = tid; i < 65536; i += nth) {
    const float* s; u16* d; int off;
    if (i < 8192)       { s = a.W1l; d = a.w1l; off = i; }
    else if (i < 16384) { s = a.W1r; d = a.w1r; off = i - 8192; }
    else if (i < 32768) { s = a.W2l; d = a.w2l; off = i - 16384; }
    else if (i < 49152) { s = a.W2r; d = a.w2r; off = i - 32768; }
    else if (i < 57344) { s = a.W3l; d = a.w3s; off = i - 49152; }
    else                { s = a.W3r; d = a.w3r; off = i - 57344; }
    ((uint2*)d)[off] = f4tob(((const float4*)s)[off]);
  }
  grid.sync();
  // P1: degree histogram
  for (int e2 = tid; e2 < N_EDGES; e2 += nth)
    atomicAdd(&a.cnt[a.ei[N_EDGES + e2]], 1);
  grid.sync();
  // P2a: per-256-chunk exclusive scan (chunk-local) + chunk totals
  for (int c = blockIdx.x; c < NBCH; c += gridDim.x) {
    int i = c * 256 + t;
    int cv = (i < N_NODES) ? a.cnt[i] : 0;
    ssc[t] = cv;
    __syncthreads();
    for (int off = 1; off < 256; off <<= 1) {
      int v = (t >= off) ? ssc[t - off] : 0;
      __syncthreads();
      ssc[t] += v;
      __syncthreads();
    }
    if (i < N_NODES) a.rowptr[i] = ssc[t] - cv;
    if (t == 255) a.bsum[c] = ssc[255];
    __syncthreads();
  }
  grid.sync();
  // P2b: block 0 scans the chunk totals (NBCH <= 256)
  if (blockIdx.x == 0) {
    int orig = (t < NBCH) ? a.bsum[t] : 0;
    ssc[t] = orig;
    __syncthreads();
    for (int off = 1; off < 256; off <<= 1) {
      int v = (t >= off) ? ssc[t - off] : 0;
      __syncthreads();
      ssc[t] += v;
      __syncthreads();
    }
    if (t < NBCH) a.bsum[t] = ssc[t] - orig;
  }
  grid.sync();
  // P2c: finalize rowptr + invc
  for (int i = tid; i < N_NODES; i += nth) {
    int cv = a.cnt[i];
    a.rowptr[i] += a.bsum[i >> 8];
    a.invc[i] = 1.0f / (float)(cv > 1 ? cv : 1);
  }
  if (tid == 0) a.rowptr[N_NODES] = N_EDGES;
  grid.sync();
  // P3: scatter src ids into CSR order + graph starts
  for (int e2 = tid; e2 < N_EDGES; e2 += nth) {
    int d = a.ei[N_EDGES + e2];
    int pos = a.rowptr[d] + atomicAdd(&a.cursor[d], 1);
    a.perm[pos] = a.ei[e2];
  }
  if (tid <= NGRAPH) {
    int lo = 0, hi = N_NODES;
    while (lo < hi) { int mid = (lo + hi) >> 1; if (a.batch[mid] < tid) lo = mid + 1; else hi = mid; }
    a.gstart[tid] = lo;
  }
}

// ================= CSR mean aggregation (R3 structure: 4 slots x 16 lanes) =================
// MODE 0: out = mean -> bf16.  MODE 1 (fused SAGE3): out = mean + Radd -> bf16.
template <int D, int MODE>
__global__ __launch_bounds__(256) void k_agg(const u16* __restrict__ x, u16* __restrict__ outp,
                                             const int* __restrict__ rowptr,
                                             const int* __restrict__ perm,
                                             const float* __restrict__ invc,
                                             const u16* __restrict__ Radd, int nn) {
  int wv = threadIdx.x >> 6, lane = threadIdx.x & 63;
  int node = blockIdx.x * 4 + wv;
  if (node >= nn) return;
  int s = rowptr[node], e = rowptr[node + 1];
  int slot = lane >> 4, lsub = lane & 15;
  constexpr int FR = D / 16;  // f32 per lane: 8 (D=128) or 16 (D=256)
  float acc[FR];
#pragma unroll
  for (int i = 0; i < FR; ++i) acc[i] = 0.f;
  const u16* xl = x + lsub * FR;

  int p = s + slot;
  for (; p + 4 < e; p += 8) {
    int src0 = perm[p];
    int src1 = perm[p + 4];
    const u16* rp0 = xl + (size_t)src0 * D;
    const u16* rp1 = xl + (size_t)src1 * D;
    if (D == 128) {
      uint4 va = *(const uint4*)rp0;
      uint4 vb = *(const uint4*)rp1;
      u32 wa[4] = {va.x, va.y, va.z, va.w}, wb[4] = {vb.x, vb.y, vb.z, vb.w};
#pragma unroll
      for (int j = 0; j < 4; ++j) {
        acc[2 * j] += __builtin_bit_cast(float, wa[j] << 16) + __builtin_bit_cast(float, wb[j] << 16);
        acc[2 * j + 1] += __builtin_bit_cast(float, wa[j] & 0xffff0000u) + __builtin_bit_cast(float, wb[j] & 0xffff0000u);
      }
    } else {
      uint4 a0 = *(const uint4*)rp0;
      uint4 a1 = *(const uint4*)(rp0 + 8);
      uint4 b0 = *(const uint4*)rp1;
      uint4 b1 = *(const uint4*)(rp1 + 8);
      u32 wa[8] = {a0.x, a0.y, a0.z, a0.w, a1.x, a1.y, a1.z, a1.w};
      u32 wb[8] = {b0.x, b0.y, b0.z, b0.w, b1.x, b1.y, b1.z, b1.w};
#pragma unroll
      for (int j = 0; j < 8; ++j) {
        acc[2 * j] += __builtin_bit_cast(float, wa[j] << 16) + __builtin_bit_cast(float, wb[j] << 16);
        acc[2 * j + 1] += __builtin_bit_cast(float, wa[j] & 0xffff0000u) + __builtin_bit_cast(float, wb[j] & 0xffff0000u);
      }
    }
  }
  if (p < e) {
    int src = perm[p];
    const u16* rp = xl + (size_t)src * D;
    if (D == 128) {
      uint4 va = *(const uint4*)rp;
      u32 wa[4] = {va.x, va.y, va.z, va.w};
#pragma unroll
      for (int j = 0; j < 4; ++j) {
        acc[2 * j] += __builtin_bit_cast(float, wa[j] << 16);
        acc[2 * j + 1] += __builtin_bit_cast(float, wa[j] & 0xffff0000u);
      }
    } else {
      uint4 a0 = *(const uint4*)rp;
      uint4 a1 = *(const uint4*)(rp + 8);
      u32 wa[8] = {a0.x, a0.y, a0.z, a0.w, a1.x, a1.y, a1.z, a1.w};
#pragma unroll
      for (int j = 0; j < 8; ++j) {
        acc[2 * j] += __builtin_bit_cast(float, wa[j] << 16);
        acc[2 * j + 1] += __builtin_bit_cast(float, wa[j] & 0xffff0000u);
      }
    }
  }

  // reduce across the 4 slots (lane bits 4,5)
#pragma unroll
  for (int i = 0; i < FR; ++i) {
    acc[i] += __shfl_xor(acc[i], 16, 64);
    acc[i] += __shfl_xor(acc[i], 32, 64);
  }

  if (slot == 0) {
    float iv = invc[node];
    float v[FR];
#pragma unroll
    for (int i = 0; i < FR; ++i) v[i] = acc[i] * iv;
    if (MODE == 1) {
      const uint4* rr = (const uint4*)(Radd + (size_t)node * D + lsub * FR);
      uint4 va = rr[0];
      u32 wa[4] = {va.x, va.y, va.z, va.w};
#pragma unroll
      for (int j = 0; j < 4; ++j) {
        v[2 * j] += __builtin_bit_cast(float, wa[j] << 16);
        v[2 * j + 1] += __builtin_bit_cast(float, wa[j] & 0xffff0000u);
      }
    }
    u32 wpk[FR / 2];
#pragma unroll
    for (int i = 0; i < FR / 2; ++i)
      wpk[i] = (u32)f2bf(v[2 * i]) | ((u32)f2bf(v[2 * i + 1]) << 16);
    uint4* o = (uint4*)(outp + (size_t)node * D + lsub * FR);
    o[0] = make_uint4(wpk[0], wpk[1], wpk[2], wpk[3]);
    if (FR == 16) o[1] = make_uint4(wpk[4], wpk[5], wpk[6], wpk[7]);
  }
}

// ================= bf16 MFMA GEMM:  out = epilogue(A1@W1^T + A2@W2^T) =================
// EPI 0: +bias, relu -> bf16 (out1, stride OUTW)
// EPI 3: dual-output: col<128 -> out1 (plain bf16); col>=128 -> out2 (+bias, bf16)
template <int OUTW, int EPI>
__global__ __launch_bounds__(256) void k_gemm(const u16* __restrict__ A1, const u16* __restrict__ W1, int K1,
                                              const u16* __restrict__ A2, const u16* __restrict__ W2, int K2,
                                              const float* __restrict__ bias,
                                              u16* __restrict__ out1, u16* __restrict__ out2, int M) {
  __shared__ u16 lsA[128 * 64];
  __shared__ u16 lsB[128 * 64];
  const int tid = threadIdx.x, lane = tid & 63, wv = tid >> 6;
  const int wm = wv >> 1, wn = wv & 1;
  const int row0 = blockIdx.x * 128, col0 = blockIdx.y * 128;

  floatx4 acc[4][4];
#pragma unroll
  for (int r = 0; r < 4; ++r)
#pragma unroll
    for (int c = 0; c < 4; ++c) acc[r][c] = 0.f;

  for (int seg = 0; seg < 2; ++seg) {
    const u16* A = seg ? A2 : A1;
    const u16* Wm = seg ? W2 : W1;
    const int K = seg ? K2 : K1;
    if (K == 0) continue;
    for (int k0 = 0; k0 < K; k0 += 64) {
      __syncthreads();
#pragma unroll
      for (int i = 0; i < 4; ++i) {
        int chunk = i * 256 + tid;
        int r = chunk >> 3;
        int kc = chunk & 7;
        int kcs = kc ^ (r & 7);        // pre-swizzle SOURCE, linear LDS dest
        int grow = row0 + r;
        grow = grow < M ? grow : M - 1;
        gld16(A + (size_t)grow * K + (k0 + kcs * 8), lsA + (size_t)(i * 256 + wv * 64) * 8);
        int wr = col0 + r;
        gld16(Wm + (size_t)wr * K + (k0 + kcs * 8), lsB + (size_t)(i * 256 + wv * 64) * 8);
      }
      __syncthreads();
#pragma unroll
      for (int kk = 0; kk < 2; ++kk) {
        bf16x8 af[4], bb[4];
        int kc = kk * 4 + (lane >> 4);
#pragma unroll
        for (int r = 0; r < 4; ++r) {
          int row = wm * 64 + r * 16 + (lane & 15);
          af[r] = __builtin_bit_cast(bf16x8, *(const short8*)(lsA + row * 64 + ((kc ^ (row & 7)) << 3)));
        }
#pragma unroll
        for (int c = 0; c < 4; ++c) {
          int row = wn * 64 + c * 16 + (lane & 15);
          bb[c] = __builtin_bit_cast(bf16x8, *(const short8*)(lsB + row * 64 + ((kc ^ (row & 7)) << 3)));
        }
#pragma unroll
        for (int r = 0; r < 4; ++r)
#pragma unroll
          for (int c = 0; c < 4; ++c)
            acc[r][c] = __builtin_amdgcn_mfma_f32_16x16x32_bf16(af[r], bb[c], acc[r][c], 0, 0, 0);
      }
    }
  }

#pragma unroll
  for (int r = 0; r < 4; ++r) {
    int rowb = row0 + wm * 64 + r * 16 + ((lane >> 4) << 2);
#pragma unroll
    for (int c = 0; c < 4; ++c) {
      int col = col0 + wn * 64 + c * 16 + (lane & 15);
#pragma unroll
      for (int j = 0; j < 4; ++j) {
        int gr = rowb + j;
        if (gr < M) {
          float v = acc[r][c][j];
          if (EPI == 0) {
            v += bias[col];
            v = v > 0.f ? v : 0.f;
            out1[(size_t)gr * OUTW + col] = f2bf(v);
          } else {  // EPI == 3
            if (col < 128) {
              out1[(size_t)gr * 128 + col] = f2bf(v);
            } else {
              v += bias[col - 128];
              out2[(size_t)gr * 128 + (col - 128)] = f2bf(v);
            }
          }
        }
      }
    }
  }
}

// ================= cooperative POST kernel: pool partials + tail + broadcast =================
struct PostArgs {
  const u16* h3;
  const int* batch;
  float* gsum;
  const int* gstart;
  const float *Wv, *bv, *ipw, *ipb, *outw, *outb, *lng, *lnb;
  float* dout;
  float* eout;
};

__global__ __launch_bounds__(256, 4) void k_post(PostArgs a) {
  cg::grid_group grid = cg::this_grid();
  __shared__ float sa[256], sb[256];
  __shared__ int sbi[64];
  __shared__ float s_mu, s_var;
  const int t = threadIdx.x;

  // P0: run-length partial sums into gsum (batch sorted)
  for (int c = blockIdx.x; c < N_NODES / 64; c += gridDim.x) {
    int n0 = c * 64;
    if (t < 64) sbi[t] = a.batch[n0 + t];
    __syncthreads();
    int col = t & 127, sub = t >> 7;
    float acc = 0.f;
    int curg = -1;
    for (int i = sub; i < 64; i += 2) {
      int g = sbi[i];
      if (g != curg) {
        if (curg >= 0) atomicAdd(&a.gsum[curg * 128 + col], acc);
        curg = g;
        acc = 0.f;
      }
      acc += bf2f(a.h3[(size_t)(n0 + i) * 128 + col]);
    }
    if (curg >= 0) atomicAdd(&a.gsum[curg * 128 + col], acc);
    __syncthreads();
  }
  grid.sync();
  // P1: per-graph tail (mean finalize + v-proj chain + LayerNorm); softmax(len-1)==1
  if (blockIdx.x < NGRAPH) {
    int b = blockIdx.x;
    if (t < 128) {
      int cg2 = a.gstart[b + 1] - a.gstart[b];
      float mean = a.gsum[b * 128 + t] / (float)(cg2 > 1 ? cg2 : 1);
      sa[t] = mean;
      a.dout[b * 128 + t] = mean;   // output 0: graph_vec
    }
    __syncthreads();
    float val = a.bv[t];
    for (int k = 0; k < 128; ++k) val += sa[k] * a.Wv[t * 128 + k];
    sb[t] = val;
    __syncthreads();
    float vv = a.ipb[512 + t];
    for (int k = 0; k < 256; ++k) vv += sb[k] * a.ipw[(size_t)(512 + t) * 256 + k];
    sa[t] = vv;
    __syncthreads();
    float at = a.outb[t];
    for (int k = 0; k < 256; ++k) at += sa[k] * a.outw[t * 256 + k];
    sb[t] = at;
    __syncthreads();
    for (int off = 128; off > 0; off >>= 1) {
      if (t < off) sb[t] += sb[t + off];
      __syncthreads();
    }
    if (t == 0) s_mu = sb[0] * (1.0f / 256.0f);
    __syncthreads();
    float d = at - s_mu;
    sb[t] = d * d;
    __syncthreads();
    for (int off = 128; off > 0; off >>= 1) {
      if (t < off) sb[t] += sb[t + off];
      __syncthreads();
    }
    if (t == 0) s_var = sb[0] * (1.0f / 256.0f);
    __syncthreads();
    float r = 1.0f / sqrtf(s_var + 1e-5f);
    a.eout[(size_t)b * 256 + t] = d * r * a.lng[t] + a.lnb[t];
  }
  grid.sync();
  // P2: broadcast per-graph embedding to all nodes
  const int nth = gridDim.x * 256;
  float4* od = (float4*)(a.dout + NGRAPH * 128);
  for (int i = blockIdx.x * 256 + t; i < N_NODES * 64; i += nth) {
    int n = i >> 6, q = i & 63;
    od[i] = ((const float4*)a.eout)[(size_t)a.batch[n] * 64 + q];
  }
}

// ================= launch =================
extern "C" void kernel_launch(void* const* d_in, const int* in_sizes, int n_in,
                              void* d_out, int out_size, void* d_ws, size_t ws_size,
                              hipStream_t stream) {
  (void)in_sizes; (void)n_in; (void)out_size; (void)ws_size;
  const float* x_bb = (const float*)d_in[0];
  const float* W1l = (const float*)d_in[2];
  const float* b1l = (const float*)d_in[3];
  const float* W1r = (const float*)d_in[4];
  const float* W2l = (const float*)d_in[5];
  const float* b2l = (const float*)d_in[6];
  const float* W2r = (const float*)d_in[7];
  const float* W3l = (const float*)d_in[8];
  const float* b3l = (const float*)d_in[9];
  const float* W3r = (const float*)d_in[10];
  const float* Wv = (const float*)d_in[15];
  const float* bv = (const float*)d_in[16];
  const float* ipw = (const float*)d_in[17];
  const float* ipb = (const float*)d_in[18];
  const float* outw = (const float*)d_in[19];
  const float* outb = (const float*)d_in[20];
  const float* lng = (const float*)d_in[21];
  const float* lnb = (const float*)d_in[22];
  const int* ei = (const int*)d_in[23];
  const int* batch = (const int*)d_in[24];
  float* dout = (float*)d_out;
  char* ws = (char*)d_ws;

  constexpr size_t O_W1L = 0;
  constexpr size_t O_W1R = O_W1L + 256 * 128 * 2;
  constexpr size_t O_W2L = O_W1R + 256 * 128 * 2;
  constexpr size_t O_W2R = O_W2L + 256 * 256 * 2;
  constexpr size_t O_W3L = O_W2R + 256 * 256 * 2;   // stacked [W3l;W3r] contiguous
  constexpr size_t O_W3R = O_W3L + 128 * 256 * 2;
  constexpr size_t O_XB = O_W3R + 128 * 256 * 2;                      // bf16 [N,128] xb -> later Pb
  constexpr size_t O_MEAN1 = O_XB + (size_t)N_NODES * 128 * 2;       // bf16 [N,128] mean1 -> later R
  constexpr size_t O_H1 = O_MEAN1 + (size_t)N_NODES * 128 * 2;       // bf16 [N,256]
  constexpr size_t O_MEAN2 = O_H1 + (size_t)N_NODES * 256 * 2;       // bf16 [N,256] mean2 -> later h3
  constexpr size_t O_H2 = O_MEAN2 + (size_t)N_NODES * 256 * 2;       // bf16 [N,256]
  constexpr size_t O_E = O_H2 + (size_t)N_NODES * 256 * 2;           // f32 [64,256]
  constexpr size_t O_CNT = O_E + 64 * 256 * 4;                       // cnt | cursor | gsum contiguous
  constexpr size_t O_CUR = O_CNT + (size_t)N_NODES * 4;
  constexpr size_t O_GSUM = O_CUR + (size_t)N_NODES * 4;             // f32 [64,128]
  constexpr size_t O_RP = O_GSUM + 64 * 128 * 4;
  constexpr size_t O_INVC = O_RP + (size_t)(N_NODES + 64) * 4;
  constexpr size_t O_BSUM = O_INVC + (size_t)N_NODES * 4;
  constexpr size_t O_GST = O_BSUM + 1024;
  constexpr size_t O_PERM = O_GST + 512;

  u16* w1l = (u16*)(ws + O_W1L);  u16* w1r = (u16*)(ws + O_W1R);
  u16* w2l = (u16*)(ws + O_W2L);  u16* w2r = (u16*)(ws + O_W2R);
  u16* w3s = (u16*)(ws + O_W3L);  u16* w3r = (u16*)(ws + O_W3R);
  u16* xb = (u16*)(ws + O_XB);
  u16* mean1 = (u16*)(ws + O_MEAN1);
  u16* h1 = (u16*)(ws + O_H1);
  u16* mean2 = (u16*)(ws + O_MEAN2);
  u16* h2 = (u16*)(ws + O_H2);
  u16* Pb = (u16*)(ws + O_XB);       // reuse xb region
  u16* Rb = (u16*)(ws + O_MEAN1);    // reuse mean1 region
  u16* h3b = (u16*)(ws + O_MEAN2);   // reuse mean2 region
  float* eb = (float*)(ws + O_E);
  int* cnt = (int*)(ws + O_CNT);
  int* cursor = (int*)(ws + O_CUR);
  float* gsum = (float*)(ws + O_GSUM);
  int* rowptr = (int*)(ws + O_RP);
  float* invc = (float*)(ws + O_INVC);
  int* bsum = (int*)(ws + O_BSUM);
  int* gstart = (int*)(ws + O_GST);
  int* perm = (int*)(ws + O_PERM);

  // --- one cooperative kernel for all setup ---
  PreArgs pa;
  pa.x_bb = x_bb; pa.W1l = W1l; pa.W1r = W1r; pa.W2l = W2l; pa.W2r = W2r;
  pa.W3l = W3l; pa.W3r = W3r; pa.ei = ei; pa.batch = batch;
  pa.xb = xb; pa.w1l = w1l; pa.w1r = w1r; pa.w2l = w2l; pa.w2r = w2r;
  pa.w3s = w3s; pa.w3r = w3r;
  pa.cnt = cnt; pa.cursor = cursor; pa.rowptr = rowptr; pa.invc = invc;
  pa.bsum = bsum; pa.gstart = gstart; pa.perm = perm;
  void* pargs[] = { &pa };
  hipLaunchCooperativeKernel((void*)k_pre, dim3(512), dim3(256), pargs, 0, stream);

  dim3 blk(256);
  // SAGE1
  k_agg<128, 0><<<N_NODES / 4, blk, 0, stream>>>(xb, mean1, rowptr, perm, invc, nullptr, N_NODES);
  k_gemm<256, 0><<<dim3(313, 2), blk, 0, stream>>>(mean1, w1l, 128, xb, w1r, 128, b1l, h1, nullptr, N_NODES);
  // SAGE2
  k_agg<256, 0><<<N_NODES / 4, blk, 0, stream>>>(h1, mean2, rowptr, perm, invc, nullptr, N_NODES);
  k_gemm<256, 0><<<dim3(313, 2), blk, 0, stream>>>(mean2, w2l, 256, h1, w2r, 256, b2l, h2, nullptr, N_NODES);
  // SAGE3: stacked GEMM -> P and R = h2@W3r+b3l; fused agg adds R
  k_gemm<128, 3><<<dim3(313, 2), blk, 0, stream>>>(h2, w3s, 256, nullptr, nullptr, 0, b3l, Pb, Rb, N_NODES);
  k_agg<128, 1><<<N_NODES / 4, blk, 0, stream>>>(Pb, h3b, rowptr, perm, invc, Rb, N_NODES);

  // --- one cooperative kernel for pool + tail + broadcast ---
  PostArgs qa;
  qa.h3 = h3b; qa.batch = batch; qa.gsum = gsum; qa.gstart = gstart;
  qa.Wv = Wv; qa.bv = bv; qa.ipw = ipw; qa.ipb = ipb;
  qa.outw = outw; qa.outb = outb; qa.lng = lng; qa.lnb = lnb;
  qa.dout = dout; qa.eout = eb;
  void* qargs[] = { &qa };
  hipLaunchCooperativeKernel((void*)k_post, dim3(512), dim3(256), qargs, 0, stream);
}

// Round 7
// 284.665 us; speedup vs baseline: 2.4502x; 2.4502x over previous
//
#include <hip/hip_runtime.h>

#define N_NODES 40000
#define N_EDGES 640000
#define NGRAPH 64

typedef unsigned short u16;
typedef unsigned int u32;
typedef __attribute__((ext_vector_type(4))) float floatx4;
typedef __attribute__((ext_vector_type(8))) short short8;
typedef __attribute__((ext_vector_type(8))) __bf16 bf16x8;

__device__ __forceinline__ float bf2f(u16 u) {
  u32 x = ((u32)u) << 16;
  return __builtin_bit_cast(float, x);
}
__device__ __forceinline__ u16 f2bf(float f) {
  u32 u = __builtin_bit_cast(u32, f);
  u += 0x7fffu + ((u >> 16) & 1u);   // RNE
  return (u16)(u >> 16);
}
__device__ __forceinline__ uint2 f4tob(float4 v) {
  u32 lo = (u32)f2bf(v.x) | ((u32)f2bf(v.y) << 16);
  u32 hi = (u32)f2bf(v.z) | ((u32)f2bf(v.w) << 16);
  return make_uint2(lo, hi);
}
__device__ __forceinline__ void gld16(const void* g, void* l) {
  __builtin_amdgcn_global_load_lds(
      (const __attribute__((address_space(1))) u32*)g,
      (__attribute__((address_space(3))) u32*)l, 16, 0, 0);
}

// ---------------- merged setup: zero + f2b(x) + f2b6(weights) + gstart ----------------
// all four pieces are mutually independent -> one grid-stride kernel, no syncs
__global__ __launch_bounds__(256) void k_setup(const float* __restrict__ x_bb, u16* __restrict__ xb,
                                               const float* __restrict__ W1l, u16* __restrict__ w1l,
                                               const float* __restrict__ W1r, u16* __restrict__ w1r,
                                               const float* __restrict__ W2l, u16* __restrict__ w2l,
                                               const float* __restrict__ W2r, u16* __restrict__ w2r,
                                               const float* __restrict__ W3l, u16* __restrict__ w3s,
                                               const float* __restrict__ W3r, u16* __restrict__ w3r,
                                               int* __restrict__ zbase,
                                               const int* __restrict__ batch, int* __restrict__ gstart) {
  const int tid = blockIdx.x * 256 + threadIdx.x;
  const int nth = gridDim.x * 256;
  // zero cnt|cursor|gsum (2N + 8192 ints)
  for (int i = tid; i < 2 * N_NODES + 8192; i += nth) zbase[i] = 0;
  // x_bb -> bf16 (N*32 float4s)
  for (int i = tid; i < N_NODES * 32; i += nth)
    ((uint2*)xb)[i] = f4tob(((const float4*)x_bb)[i]);
  // weights -> bf16 (65536 float4s)
  for (int i = tid; i < 65536; i += nth) {
    const float* s; u16* d; int off;
    if (i < 8192)       { s = W1l; d = w1l; off = i; }
    else if (i < 16384) { s = W1r; d = w1r; off = i - 8192; }
    else if (i < 32768) { s = W2l; d = w2l; off = i - 16384; }
    else if (i < 49152) { s = W2r; d = w2r; off = i - 32768; }
    else if (i < 57344) { s = W3l; d = w3s; off = i - 49152; }
    else                { s = W3r; d = w3r; off = i - 57344; }
    ((uint2*)d)[off] = f4tob(((const float4*)s)[off]);
  }
  // graph starts (batch sorted)
  if (tid <= NGRAPH) {
    int lo = 0, hi = N_NODES;
    while (lo < hi) { int mid = (lo + hi) >> 1; if (batch[mid] < tid) lo = mid + 1; else hi = mid; }
    gstart[tid] = lo;
  }
}

// ---------------- CSR build ----------------
__global__ void k_hist(const int* __restrict__ ei, int* __restrict__ cnt) {
  int e = blockIdx.x * 256 + threadIdx.x;
  int d = ei[N_EDGES + e];
  atomicAdd(&cnt[d], 1);
}
__global__ void k_blocksum(const int* __restrict__ cnt, int* __restrict__ bsum, int n) {
  __shared__ int s[256];
  int t = threadIdx.x, i = blockIdx.x * 256 + t;
  s[t] = (i < n) ? cnt[i] : 0;
  __syncthreads();
  for (int off = 128; off > 0; off >>= 1) {
    if (t < off) s[t] += s[t + off];
    __syncthreads();
  }
  if (t == 0) bsum[blockIdx.x] = s[0];
}
__global__ void k_scan_small(int* bsum, int n) {
  __shared__ int s[256];
  int t = threadIdx.x;
  int orig = (t < n) ? bsum[t] : 0;
  s[t] = orig;
  __syncthreads();
  for (int off = 1; off < 256; off <<= 1) {
    int v = (t >= off) ? s[t - off] : 0;
    __syncthreads();
    s[t] += v;
    __syncthreads();
  }
  if (t < n) bsum[t] = s[t] - orig;  // exclusive
}
__global__ void k_rowptr(const int* __restrict__ cnt, const int* __restrict__ bsum,
                         int* __restrict__ rowptr, float* __restrict__ invc, int n, int total) {
  __shared__ int s[256];
  int t = threadIdx.x, i = blockIdx.x * 256 + t;
  int c = (i < n) ? cnt[i] : 0;
  s[t] = c;
  __syncthreads();
  for (int off = 1; off < 256; off <<= 1) {
    int v = (t >= off) ? s[t - off] : 0;
    __syncthreads();
    s[t] += v;
    __syncthreads();
  }
  if (i < n) {
    rowptr[i] = bsum[blockIdx.x] + s[t] - c;   // exclusive
    invc[i] = 1.0f / (float)(c > 1 ? c : 1);
  }
  if (i == 0) rowptr[n] = total;
}
__global__ void k_scatter(const int* __restrict__ ei, const int* __restrict__ rowptr,
                          int* __restrict__ cursor, int* __restrict__ perm) {
  int e = blockIdx.x * 256 + threadIdx.x;
  int d = ei[N_EDGES + e];
  int srcn = ei[e];
  int pos = rowptr[d] + atomicAdd(&cursor[d], 1);
  perm[pos] = srcn;
}

// ---------------- CSR mean aggregation (R3 structure: 4 slots x 16 lanes, pair-unrolled) ----------------
// MODE 0: out = mean -> bf16.  MODE 1 (fused SAGE3): out = mean + Radd -> bf16.
template <int D, int MODE>
__global__ __launch_bounds__(256) void k_agg(const u16* __restrict__ x, u16* __restrict__ outp,
                                             const int* __restrict__ rowptr,
                                             const int* __restrict__ perm,
                                             const float* __restrict__ invc,
                                             const u16* __restrict__ Radd, int nn) {
  int wv = threadIdx.x >> 6, lane = threadIdx.x & 63;
  int node = blockIdx.x * 4 + wv;
  if (node >= nn) return;
  int s = rowptr[node], e = rowptr[node + 1];
  int slot = lane >> 4, lsub = lane & 15;
  constexpr int FR = D / 16;  // f32 per lane: 8 (D=128) or 16 (D=256)
  float acc[FR];
#pragma unroll
  for (int i = 0; i < FR; ++i) acc[i] = 0.f;
  const u16* xl = x + lsub * FR;

  int p = s + slot;
  for (; p + 4 < e; p += 8) {
    int src0 = perm[p];
    int src1 = perm[p + 4];
    const u16* rp0 = xl + (size_t)src0 * D;
    const u16* rp1 = xl + (size_t)src1 * D;
    if (D == 128) {
      uint4 va = *(const uint4*)rp0;
      uint4 vb = *(const uint4*)rp1;
      u32 wa[4] = {va.x, va.y, va.z, va.w}, wb[4] = {vb.x, vb.y, vb.z, vb.w};
#pragma unroll
      for (int j = 0; j < 4; ++j) {
        acc[2 * j] += __builtin_bit_cast(float, wa[j] << 16) + __builtin_bit_cast(float, wb[j] << 16);
        acc[2 * j + 1] += __builtin_bit_cast(float, wa[j] & 0xffff0000u) + __builtin_bit_cast(float, wb[j] & 0xffff0000u);
      }
    } else {
      uint4 a0 = *(const uint4*)rp0;
      uint4 a1 = *(const uint4*)(rp0 + 8);
      uint4 b0 = *(const uint4*)rp1;
      uint4 b1 = *(const uint4*)(rp1 + 8);
      u32 wa[8] = {a0.x, a0.y, a0.z, a0.w, a1.x, a1.y, a1.z, a1.w};
      u32 wb[8] = {b0.x, b0.y, b0.z, b0.w, b1.x, b1.y, b1.z, b1.w};
#pragma unroll
      for (int j = 0; j < 8; ++j) {
        acc[2 * j] += __builtin_bit_cast(float, wa[j] << 16) + __builtin_bit_cast(float, wb[j] << 16);
        acc[2 * j + 1] += __builtin_bit_cast(float, wa[j] & 0xffff0000u) + __builtin_bit_cast(float, wb[j] & 0xffff0000u);
      }
    }
  }
  if (p < e) {
    int src = perm[p];
    const u16* rp = xl + (size_t)src * D;
    if (D == 128) {
      uint4 va = *(const uint4*)rp;
      u32 wa[4] = {va.x, va.y, va.z, va.w};
#pragma unroll
      for (int j = 0; j < 4; ++j) {
        acc[2 * j] += __builtin_bit_cast(float, wa[j] << 16);
        acc[2 * j + 1] += __builtin_bit_cast(float, wa[j] & 0xffff0000u);
      }
    } else {
      uint4 a0 = *(const uint4*)rp;
      uint4 a1 = *(const uint4*)(rp + 8);
      u32 wa[8] = {a0.x, a0.y, a0.z, a0.w, a1.x, a1.y, a1.z, a1.w};
#pragma unroll
      for (int j = 0; j < 8; ++j) {
        acc[2 * j] += __builtin_bit_cast(float, wa[j] << 16);
        acc[2 * j + 1] += __builtin_bit_cast(float, wa[j] & 0xffff0000u);
      }
    }
  }

  // reduce across the 4 slots (lane bits 4,5)
#pragma unroll
  for (int i = 0; i < FR; ++i) {
    acc[i] += __shfl_xor(acc[i], 16, 64);
    acc[i] += __shfl_xor(acc[i], 32, 64);
  }

  if (slot == 0) {
    float iv = invc[node];
    float v[FR];
#pragma unroll
    for (int i = 0; i < FR; ++i) v[i] = acc[i] * iv;
    if (MODE == 1) {
      const uint4* rr = (const uint4*)(Radd + (size_t)node * D + lsub * FR);
      uint4 va = rr[0];
      u32 wa[4] = {va.x, va.y, va.z, va.w};
#pragma unroll
      for (int j = 0; j < 4; ++j) {
        v[2 * j] += __builtin_bit_cast(float, wa[j] << 16);
        v[2 * j + 1] += __builtin_bit_cast(float, wa[j] & 0xffff0000u);
      }
    }
    u32 wpk[FR / 2];
#pragma unroll
    for (int i = 0; i < FR / 2; ++i)
      wpk[i] = (u32)f2bf(v[2 * i]) | ((u32)f2bf(v[2 * i + 1]) << 16);
    uint4* o = (uint4*)(outp + (size_t)node * D + lsub * FR);
    o[0] = make_uint4(wpk[0], wpk[1], wpk[2], wpk[3]);
    if (FR == 16) o[1] = make_uint4(wpk[4], wpk[5], wpk[6], wpk[7]);
  }
}

// ---------------- bf16 MFMA GEMM:  out = epilogue(A1@W1^T + A2@W2^T) ----------------
// EPI 0: +bias, relu -> bf16 (out1, stride OUTW)
// EPI 3: dual-output: col<128 -> out1 (plain bf16); col>=128 -> out2 (+bias, bf16)
template <int OUTW, int EPI>
__global__ __launch_bounds__(256) void k_gemm(const u16* __restrict__ A1, const u16* __restrict__ W1, int K1,
                                              const u16* __restrict__ A2, const u16* __restrict__ W2, int K2,
                                              const float* __restrict__ bias,
                                              u16* __restrict__ out1, u16* __restrict__ out2, int M) {
  __shared__ u16 lsA[128 * 64];
  __shared__ u16 lsB[128 * 64];
  const int tid = threadIdx.x, lane = tid & 63, wv = tid >> 6;
  const int wm = wv >> 1, wn = wv & 1;
  const int row0 = blockIdx.x * 128, col0 = blockIdx.y * 128;

  floatx4 acc[4][4];
#pragma unroll
  for (int r = 0; r < 4; ++r)
#pragma unroll
    for (int c = 0; c < 4; ++c) acc[r][c] = 0.f;

  for (int seg = 0; seg < 2; ++seg) {
    const u16* A = seg ? A2 : A1;
    const u16* Wm = seg ? W2 : W1;
    const int K = seg ? K2 : K1;
    if (K == 0) continue;
    for (int k0 = 0; k0 < K; k0 += 64) {
      __syncthreads();
#pragma unroll
      for (int i = 0; i < 4; ++i) {
        int chunk = i * 256 + tid;
        int r = chunk >> 3;
        int kc = chunk & 7;
        int kcs = kc ^ (r & 7);        // pre-swizzle SOURCE, linear LDS dest
        int grow = row0 + r;
        grow = grow < M ? grow : M - 1;
        gld16(A + (size_t)grow * K + (k0 + kcs * 8), lsA + (size_t)(i * 256 + wv * 64) * 8);
        int wr = col0 + r;
        gld16(Wm + (size_t)wr * K + (k0 + kcs * 8), lsB + (size_t)(i * 256 + wv * 64) * 8);
      }
      __syncthreads();
#pragma unroll
      for (int kk = 0; kk < 2; ++kk) {
        bf16x8 af[4], bb[4];
        int kc = kk * 4 + (lane >> 4);
#pragma unroll
        for (int r = 0; r < 4; ++r) {
          int row = wm * 64 + r * 16 + (lane & 15);
          af[r] = __builtin_bit_cast(bf16x8, *(const short8*)(lsA + row * 64 + ((kc ^ (row & 7)) << 3)));
        }
#pragma unroll
        for (int c = 0; c < 4; ++c) {
          int row = wn * 64 + c * 16 + (lane & 15);
          bb[c] = __builtin_bit_cast(bf16x8, *(const short8*)(lsB + row * 64 + ((kc ^ (row & 7)) << 3)));
        }
#pragma unroll
        for (int r = 0; r < 4; ++r)
#pragma unroll
          for (int c = 0; c < 4; ++c)
            acc[r][c] = __builtin_amdgcn_mfma_f32_16x16x32_bf16(af[r], bb[c], acc[r][c], 0, 0, 0);
      }
    }
  }

#pragma unroll
  for (int r = 0; r < 4; ++r) {
    int rowb = row0 + wm * 64 + r * 16 + ((lane >> 4) << 2);
#pragma unroll
    for (int c = 0; c < 4; ++c) {
      int col = col0 + wn * 64 + c * 16 + (lane & 15);
#pragma unroll
      for (int j = 0; j < 4; ++j) {
        int gr = rowb + j;
        if (gr < M) {
          float v = acc[r][c][j];
          if (EPI == 0) {
            v += bias[col];
            v = v > 0.f ? v : 0.f;
            out1[(size_t)gr * OUTW + col] = f2bf(v);
          } else {  // EPI == 3
            if (col < 128) {
              out1[(size_t)gr * 128 + col] = f2bf(v);
            } else {
              v += bias[col - 128];
              out2[(size_t)gr * 128 + (col - 128)] = f2bf(v);
            }
          }
        }
      }
    }
  }
}

// ---------------- global mean pool, phase 1: run-length partial sums (bf16 in) ----------------
__global__ __launch_bounds__(256) void k_pool_part(const u16* __restrict__ h3,
                                                   const int* __restrict__ batch,
                                                   float* __restrict__ gsum) {
  __shared__ int sb[64];
  int t = threadIdx.x;
  int n0 = blockIdx.x * 64;
  if (t < 64) sb[t] = batch[n0 + t];
  __syncthreads();
  int col = t & 127, sub = t >> 7;
  float acc = 0.f;
  int curg = -1;
  for (int i = sub; i < 64; i += 2) {
    int g = sb[i];
    if (g != curg) {
      if (curg >= 0) atomicAdd(&gsum[curg * 128 + col], acc);
      curg = g;
      acc = 0.f;
    }
    acc += bf2f(h3[(size_t)(n0 + i) * 128 + col]);
  }
  if (curg >= 0) atomicAdd(&gsum[curg * 128 + col], acc);
}

// ---------------- per-graph tail: mean finalize + v-proj chain + LayerNorm ----------------
__global__ __launch_bounds__(256) void k_tail(const float* __restrict__ gsum, const int* __restrict__ gstart,
                                              const float* __restrict__ Wv,
                                              const float* __restrict__ bv, const float* __restrict__ ipw,
                                              const float* __restrict__ ipb, const float* __restrict__ outw,
                                              const float* __restrict__ outb, const float* __restrict__ lng,
                                              const float* __restrict__ lnb, float* __restrict__ dout,
                                              float* __restrict__ eout) {
  __shared__ float sa[256], sb[256];
  __shared__ float s_mu, s_var;
  int b = blockIdx.x, t = threadIdx.x;
  if (t < 128) {
    int cg = gstart[b + 1] - gstart[b];
    float mean = gsum[b * 128 + t] / (float)(cg > 1 ? cg : 1);
    sa[t] = mean;
    dout[b * 128 + t] = mean;   // output 0: graph_vec
  }
  __syncthreads();
  float val = bv[t];
  for (int k = 0; k < 128; ++k) val += sa[k] * Wv[t * 128 + k];
  sb[t] = val;
  __syncthreads();
  float vv = ipb[512 + t];
  for (int k = 0; k < 256; ++k) vv += sb[k] * ipw[(size_t)(512 + t) * 256 + k];
  sa[t] = vv;
  __syncthreads();
  float at = outb[t];
  for (int k = 0; k < 256; ++k) at += sa[k] * outw[t * 256 + k];
  sb[t] = at;
  __syncthreads();
  for (int off = 128; off > 0; off >>= 1) {
    if (t < off) sb[t] += sb[t + off];
    __syncthreads();
  }
  if (t == 0) s_mu = sb[0] * (1.0f / 256.0f);
  __syncthreads();
  float d = at - s_mu;
  sb[t] = d * d;
  __syncthreads();
  for (int off = 128; off > 0; off >>= 1) {
    if (t < off) sb[t] += sb[t + off];
    __syncthreads();
  }
  if (t == 0) s_var = sb[0] * (1.0f / 256.0f);
  __syncthreads();
  float r = 1.0f / sqrtf(s_var + 1e-5f);
  eout[(size_t)b * 256 + t] = d * r * lng[t] + lnb[t];
}

// ---------------- broadcast per-graph embedding to nodes ----------------
__global__ void k_scat_out(const float* __restrict__ eb, const int* __restrict__ batch,
                           float* __restrict__ dout) {
  int i = blockIdx.x * 256 + threadIdx.x;
  int n = i >> 6, q = i & 63;
  float4 v = ((const float4*)eb)[(size_t)batch[n] * 64 + q];
  ((float4*)(dout + NGRAPH * 128))[i] = v;
}

// ---------------- launch ----------------
extern "C" void kernel_launch(void* const* d_in, const int* in_sizes, int n_in,
                              void* d_out, int out_size, void* d_ws, size_t ws_size,
                              hipStream_t stream) {
  (void)in_sizes; (void)n_in; (void)out_size; (void)ws_size;
  const float* x_bb = (const float*)d_in[0];
  const float* W1l = (const float*)d_in[2];
  const float* b1l = (const float*)d_in[3];
  const float* W1r = (const float*)d_in[4];
  const float* W2l = (const float*)d_in[5];
  const float* b2l = (const float*)d_in[6];
  const float* W2r = (const float*)d_in[7];
  const float* W3l = (const float*)d_in[8];
  const float* b3l = (const float*)d_in[9];
  const float* W3r = (const float*)d_in[10];
  const float* Wv = (const float*)d_in[15];
  const float* bv = (const float*)d_in[16];
  const float* ipw = (const float*)d_in[17];
  const float* ipb = (const float*)d_in[18];
  const float* outw = (const float*)d_in[19];
  const float* outb = (const float*)d_in[20];
  const float* lng = (const float*)d_in[21];
  const float* lnb = (const float*)d_in[22];
  const int* ei = (const int*)d_in[23];
  const int* batch = (const int*)d_in[24];
  float* dout = (float*)d_out;
  char* ws = (char*)d_ws;

  constexpr size_t O_W1L = 0;
  constexpr size_t O_W1R = O_W1L + 256 * 128 * 2;
  constexpr size_t O_W2L = O_W1R + 256 * 128 * 2;
  constexpr size_t O_W2R = O_W2L + 256 * 256 * 2;
  constexpr size_t O_W3L = O_W2R + 256 * 256 * 2;   // stacked [W3l;W3r] contiguous
  constexpr size_t O_W3R = O_W3L + 128 * 256 * 2;
  constexpr size_t O_XB = O_W3R + 128 * 256 * 2;                      // bf16 [N,128] xb -> later Pb
  constexpr size_t O_MEAN1 = O_XB + (size_t)N_NODES * 128 * 2;       // bf16 [N,128] mean1 -> later R
  constexpr size_t O_H1 = O_MEAN1 + (size_t)N_NODES * 128 * 2;       // bf16 [N,256]
  constexpr size_t O_MEAN2 = O_H1 + (size_t)N_NODES * 256 * 2;       // bf16 [N,256] mean2 -> later h3
  constexpr size_t O_H2 = O_MEAN2 + (size_t)N_NODES * 256 * 2;       // bf16 [N,256]
  constexpr size_t O_E = O_H2 + (size_t)N_NODES * 256 * 2;           // f32 [64,256]
  constexpr size_t O_CNT = O_E + 64 * 256 * 4;                       // cnt | cursor | gsum contiguous (zeroed together)
  constexpr size_t O_CUR = O_CNT + (size_t)N_NODES * 4;
  constexpr size_t O_GSUM = O_CUR + (size_t)N_NODES * 4;             // f32 [64,128]
  constexpr size_t O_RP = O_GSUM + 64 * 128 * 4;
  constexpr size_t O_INVC = O_RP + (size_t)(N_NODES + 64) * 4;
  constexpr size_t O_BSUM = O_INVC + (size_t)N_NODES * 4;
  constexpr size_t O_GST = O_BSUM + 1024;
  constexpr size_t O_PERM = O_GST + 512;

  u16* w1l = (u16*)(ws + O_W1L);  u16* w1r = (u16*)(ws + O_W1R);
  u16* w2l = (u16*)(ws + O_W2L);  u16* w2r = (u16*)(ws + O_W2R);
  u16* w3s = (u16*)(ws + O_W3L);  u16* w3r = (u16*)(ws + O_W3R);
  u16* xb = (u16*)(ws + O_XB);
  u16* mean1 = (u16*)(ws + O_MEAN1);
  u16* h1 = (u16*)(ws + O_H1);
  u16* mean2 = (u16*)(ws + O_MEAN2);
  u16* h2 = (u16*)(ws + O_H2);
  u16* Pb = (u16*)(ws + O_XB);       // reuse xb region
  u16* Rb = (u16*)(ws + O_MEAN1);    // reuse mean1 region
  u16* h3b = (u16*)(ws + O_MEAN2);   // reuse mean2 region
  float* eb = (float*)(ws + O_E);
  int* cnt = (int*)(ws + O_CNT);
  int* cursor = (int*)(ws + O_CUR);
  float* gsum = (float*)(ws + O_GSUM);
  int* rowptr = (int*)(ws + O_RP);
  float* invc = (float*)(ws + O_INVC);
  int* bsum = (int*)(ws + O_BSUM);
  int* gstart = (int*)(ws + O_GST);
  int* perm = (int*)(ws + O_PERM);

  const int NB = (N_NODES + 255) / 256;  // 157
  dim3 blk(256);

  // merged setup (zero + converts + gstart), then CSR chain
  k_setup<<<512, blk, 0, stream>>>(x_bb, xb, W1l, w1l, W1r, w1r, W2l, w2l, W2r, w2r,
                                   W3l, w3s, W3r, w3r, cnt, batch, gstart);
  k_hist<<<N_EDGES / 256, blk, 0, stream>>>(ei, cnt);
  k_blocksum<<<NB, blk, 0, stream>>>(cnt, bsum, N_NODES);
  k_scan_small<<<1, blk, 0, stream>>>(bsum, NB);
  k_rowptr<<<NB, blk, 0, stream>>>(cnt, bsum, rowptr, invc, N_NODES, N_EDGES);
  k_scatter<<<N_EDGES / 256, blk, 0, stream>>>(ei, rowptr, cursor, perm);

  // SAGE1
  k_agg<128, 0><<<N_NODES / 4, blk, 0, stream>>>(xb, mean1, rowptr, perm, invc, nullptr, N_NODES);
  k_gemm<256, 0><<<dim3(313, 2), blk, 0, stream>>>(mean1, w1l, 128, xb, w1r, 128, b1l, h1, nullptr, N_NODES);
  // SAGE2
  k_agg<256, 0><<<N_NODES / 4, blk, 0, stream>>>(h1, mean2, rowptr, perm, invc, nullptr, N_NODES);
  k_gemm<256, 0><<<dim3(313, 2), blk, 0, stream>>>(mean2, w2l, 256, h1, w2r, 256, b2l, h2, nullptr, N_NODES);
  // SAGE3: stacked GEMM -> P and R = h2@W3r+b3l; fused agg adds R
  k_gemm<128, 3><<<dim3(313, 2), blk, 0, stream>>>(h2, w3s, 256, nullptr, nullptr, 0, b3l, Pb, Rb, N_NODES);
  k_agg<128, 1><<<N_NODES / 4, blk, 0, stream>>>(Pb, h3b, rowptr, perm, invc, Rb, N_NODES);

  // pool (partial sums) + per-graph tail + broadcast
  k_pool_part<<<N_NODES / 64, blk, 0, stream>>>(h3b, batch, gsum);
  k_tail<<<NGRAPH, blk, 0, stream>>>(gsum, gstart, Wv, bv, ipw, ipb, outw, outb, lng, lnb, dout, eb);
  k_scat_out<<<N_NODES * 64 / 256, blk, 0, stream>>>(eb, batch, dout);
}

// Round 8
// 259.420 us; speedup vs baseline: 2.6886x; 1.0973x over previous
//
#include <hip/hip_runtime.h>

#define N_NODES 40000
#define N_EDGES 640000
#define NGRAPH 64

typedef unsigned short u16;
typedef unsigned char u8;
typedef unsigned int u32;
typedef __attribute__((ext_vector_type(2))) float floatx2;
typedef __attribute__((ext_vector_type(4))) float floatx4;
typedef __attribute__((ext_vector_type(8))) short short8;
typedef __attribute__((ext_vector_type(8))) __bf16 bf16x8;

__device__ __forceinline__ float bf2f(u16 u) {
  u32 x = ((u32)u) << 16;
  return __builtin_bit_cast(float, x);
}
__device__ __forceinline__ u16 f2bf(float f) {
  u32 u = __builtin_bit_cast(u32, f);
  u += 0x7fffu + ((u >> 16) & 1u);   // RNE
  return (u16)(u >> 16);
}
__device__ __forceinline__ uint2 f4tob(float4 v) {
  u32 lo = (u32)f2bf(v.x) | ((u32)f2bf(v.y) << 16);
  u32 hi = (u32)f2bf(v.z) | ((u32)f2bf(v.w) << 16);
  return make_uint2(lo, hi);
}
// fp8 e4m3 (OCP on gfx950) HW converts; word-select must be a literal
__device__ __forceinline__ u32 fp8pk_lo(float a, float b, u32 old) {
  return (u32)__builtin_amdgcn_cvt_pk_fp8_f32(a, b, (int)old, false);
}
__device__ __forceinline__ u32 fp8pk_hi(float a, float b, u32 old) {
  return (u32)__builtin_amdgcn_cvt_pk_fp8_f32(a, b, (int)old, true);
}
__device__ __forceinline__ floatx2 fp8up_lo(u32 v) {
  return __builtin_amdgcn_cvt_pk_f32_fp8((int)v, false);
}
__device__ __forceinline__ floatx2 fp8up_hi(u32 v) {
  return __builtin_amdgcn_cvt_pk_f32_fp8((int)v, true);
}
__device__ __forceinline__ void gld16(const void* g, void* l) {
  __builtin_amdgcn_global_load_lds(
      (const __attribute__((address_space(1))) u32*)g,
      (__attribute__((address_space(3))) u32*)l, 16, 0, 0);
}

// ---------------- merged setup: zero + f2b(x)(+fp8) + f2b6(weights) + gstart ----------------
__global__ __launch_bounds__(256) void k_setup(const float* __restrict__ x_bb, u16* __restrict__ xb,
                                               u8* __restrict__ xq,
                                               const float* __restrict__ W1l, u16* __restrict__ w1l,
                                               const float* __restrict__ W1r, u16* __restrict__ w1r,
                                               const float* __restrict__ W2l, u16* __restrict__ w2l,
                                               const float* __restrict__ W2r, u16* __restrict__ w2r,
                                               const float* __restrict__ W3l, u16* __restrict__ w3s,
                                               const float* __restrict__ W3r, u16* __restrict__ w3r,
                                               int* __restrict__ zbase,
                                               const int* __restrict__ batch, int* __restrict__ gstart) {
  const int tid = blockIdx.x * 256 + threadIdx.x;
  const int nth = gridDim.x * 256;
  for (int i = tid; i < 2 * N_NODES + 8192; i += nth) zbase[i] = 0;
  for (int i = tid; i < N_NODES * 32; i += nth) {
    float4 v = ((const float4*)x_bb)[i];
    ((uint2*)xb)[i] = f4tob(v);
    if (xq) {
      u32 q = fp8pk_lo(v.x, v.y, 0);
      q = fp8pk_hi(v.z, v.w, q);
      ((u32*)xq)[i] = q;
    }
  }
  for (int i = tid; i < 65536; i += nth) {
    const float* s; u16* d; int off;
    if (i < 8192)       { s = W1l; d = w1l; off = i; }
    else if (i < 16384) { s = W1r; d = w1r; off = i - 8192; }
    else if (i < 32768) { s = W2l; d = w2l; off = i - 16384; }
    else if (i < 49152) { s = W2r; d = w2r; off = i - 32768; }
    else if (i < 57344) { s = W3l; d = w3s; off = i - 49152; }
    else                { s = W3r; d = w3r; off = i - 57344; }
    ((uint2*)d)[off] = f4tob(((const float4*)s)[off]);
  }
  if (tid <= NGRAPH) {
    int lo = 0, hi = N_NODES;
    while (lo < hi) { int mid = (lo + hi) >> 1; if (batch[mid] < tid) lo = mid + 1; else hi = mid; }
    gstart[tid] = lo;
  }
}

// ---------------- CSR build ----------------
__global__ void k_hist(const int* __restrict__ ei, int* __restrict__ cnt) {
  int e = blockIdx.x * 256 + threadIdx.x;
  int d = ei[N_EDGES + e];
  atomicAdd(&cnt[d], 1);
}
__global__ void k_blocksum(const int* __restrict__ cnt, int* __restrict__ bsum, int n) {
  __shared__ int s[256];
  int t = threadIdx.x, i = blockIdx.x * 256 + t;
  s[t] = (i < n) ? cnt[i] : 0;
  __syncthreads();
  for (int off = 128; off > 0; off >>= 1) {
    if (t < off) s[t] += s[t + off];
    __syncthreads();
  }
  if (t == 0) bsum[blockIdx.x] = s[0];
}
__global__ void k_scan_small(int* bsum, int n) {
  __shared__ int s[256];
  int t = threadIdx.x;
  int orig = (t < n) ? bsum[t] : 0;
  s[t] = orig;
  __syncthreads();
  for (int off = 1; off < 256; off <<= 1) {
    int v = (t >= off) ? s[t - off] : 0;
    __syncthreads();
    s[t] += v;
    __syncthreads();
  }
  if (t < n) bsum[t] = s[t] - orig;  // exclusive
}
__global__ void k_rowptr(const int* __restrict__ cnt, const int* __restrict__ bsum,
                         int* __restrict__ rowptr, float* __restrict__ invc, int n, int total) {
  __shared__ int s[256];
  int t = threadIdx.x, i = blockIdx.x * 256 + t;
  int c = (i < n) ? cnt[i] : 0;
  s[t] = c;
  __syncthreads();
  for (int off = 1; off < 256; off <<= 1) {
    int v = (t >= off) ? s[t - off] : 0;
    __syncthreads();
    s[t] += v;
    __syncthreads();
  }
  if (i < n) {
    rowptr[i] = bsum[blockIdx.x] + s[t] - c;   // exclusive
    invc[i] = 1.0f / (float)(c > 1 ? c : 1);
  }
  if (i == 0) rowptr[n] = total;
}
__global__ void k_scatter(const int* __restrict__ ei, const int* __restrict__ rowptr,
                          int* __restrict__ cursor, int* __restrict__ perm) {
  int e = blockIdx.x * 256 + threadIdx.x;
  int d = ei[N_EDGES + e];
  int srcn = ei[e];
  int pos = rowptr[d] + atomicAdd(&cursor[d], 1);
  perm[pos] = srcn;
}

// ---------------- CSR mean aggregation (4 slots x 16 lanes, pair-unrolled) ----------------
// QT 0: bf16 input rows.  QT 1: fp8 e4m3 input rows (half the cache lines per edge).
// MODE 0: out = mean -> bf16.  MODE 1 (fused SAGE3, D=128 only): out = mean + Radd -> bf16.
template <int D, int MODE, int QT>
__global__ __launch_bounds__(256) void k_agg(const void* __restrict__ xv, u16* __restrict__ outp,
                                             const int* __restrict__ rowptr,
                                             const int* __restrict__ perm,
                                             const float* __restrict__ invc,
                                             const u16* __restrict__ Radd, int nn) {
  int wv = threadIdx.x >> 6, lane = threadIdx.x & 63;
  int node = blockIdx.x * 4 + wv;
  if (node >= nn) return;
  int s = rowptr[node], e = rowptr[node + 1];
  int slot = lane >> 4, lsub = lane & 15;
  constexpr int FR = D / 16;  // cols per lane: 8 (D=128) or 16 (D=256)
  float acc[FR];
#pragma unroll
  for (int i = 0; i < FR; ++i) acc[i] = 0.f;

  int p = s + slot;
  if constexpr (QT == 1) {
    const u8* xl = (const u8*)xv + lsub * FR;
    constexpr int NW = FR / 4;  // u32 words per lane per row
    for (; p + 4 < e; p += 8) {
      int s0 = perm[p], s1 = perm[p + 4];
      const u8* r0 = xl + (size_t)s0 * D;
      const u8* r1 = xl + (size_t)s1 * D;
      u32 wa[NW], wb[NW];
      if constexpr (D == 128) {
        uint2 a = *(const uint2*)r0; wa[0] = a.x; wa[1] = a.y;
        uint2 b = *(const uint2*)r1; wb[0] = b.x; wb[1] = b.y;
      } else {
        uint4 a = *(const uint4*)r0; wa[0] = a.x; wa[1] = a.y; wa[2] = a.z; wa[3] = a.w;
        uint4 b = *(const uint4*)r1; wb[0] = b.x; wb[1] = b.y; wb[2] = b.z; wb[3] = b.w;
      }
#pragma unroll
      for (int j = 0; j < NW; ++j) {
        floatx2 l0 = fp8up_lo(wa[j]), h0 = fp8up_hi(wa[j]);
        floatx2 l1 = fp8up_lo(wb[j]), h1 = fp8up_hi(wb[j]);
        acc[4 * j]     += l0[0] + l1[0];
        acc[4 * j + 1] += l0[1] + l1[1];
        acc[4 * j + 2] += h0[0] + h1[0];
        acc[4 * j + 3] += h0[1] + h1[1];
      }
    }
    if (p < e) {
      int s0 = perm[p];
      const u8* r0 = xl + (size_t)s0 * D;
      u32 wa[NW];
      if constexpr (D == 128) {
        uint2 a = *(const uint2*)r0; wa[0] = a.x; wa[1] = a.y;
      } else {
        uint4 a = *(const uint4*)r0; wa[0] = a.x; wa[1] = a.y; wa[2] = a.z; wa[3] = a.w;
      }
#pragma unroll
      for (int j = 0; j < NW; ++j) {
        floatx2 l0 = fp8up_lo(wa[j]), h0 = fp8up_hi(wa[j]);
        acc[4 * j]     += l0[0];
        acc[4 * j + 1] += l0[1];
        acc[4 * j + 2] += h0[0];
        acc[4 * j + 3] += h0[1];
      }
    }
  } else {
    const u16* xl = (const u16*)xv + lsub * FR;
    for (; p + 4 < e; p += 8) {
      int src0 = perm[p];
      int src1 = perm[p + 4];
      const u16* rp0 = xl + (size_t)src0 * D;
      const u16* rp1 = xl + (size_t)src1 * D;
      if (D == 128) {
        uint4 va = *(const uint4*)rp0;
        uint4 vb = *(const uint4*)rp1;
        u32 wa[4] = {va.x, va.y, va.z, va.w}, wb[4] = {vb.x, vb.y, vb.z, vb.w};
#pragma unroll
        for (int j = 0; j < 4; ++j) {
          acc[2 * j] += __builtin_bit_cast(float, wa[j] << 16) + __builtin_bit_cast(float, wb[j] << 16);
          acc[2 * j + 1] += __builtin_bit_cast(float, wa[j] & 0xffff0000u) + __builtin_bit_cast(float, wb[j] & 0xffff0000u);
        }
      } else {
        uint4 a0 = *(const uint4*)rp0;
        uint4 a1 = *(const uint4*)(rp0 + 8);
        uint4 b0 = *(const uint4*)rp1;
        uint4 b1 = *(const uint4*)(rp1 + 8);
        u32 wa[8] = {a0.x, a0.y, a0.z, a0.w, a1.x, a1.y, a1.z, a1.w};
        u32 wb[8] = {b0.x, b0.y, b0.z, b0.w, b1.x, b1.y, b1.z, b1.w};
#pragma unroll
        for (int j = 0; j < 8; ++j) {
          acc[2 * j] += __builtin_bit_cast(float, wa[j] << 16) + __builtin_bit_cast(float, wb[j] << 16);
          acc[2 * j + 1] += __builtin_bit_cast(float, wa[j] & 0xffff0000u) + __builtin_bit_cast(float, wb[j] & 0xffff0000u);
        }
      }
    }
    if (p < e) {
      int src = perm[p];
      const u16* rp = xl + (size_t)src * D;
      if (D == 128) {
        uint4 va = *(const uint4*)rp;
        u32 wa[4] = {va.x, va.y, va.z, va.w};
#pragma unroll
        for (int j = 0; j < 4; ++j) {
          acc[2 * j] += __builtin_bit_cast(float, wa[j] << 16);
          acc[2 * j + 1] += __builtin_bit_cast(float, wa[j] & 0xffff0000u);
        }
      } else {
        uint4 a0 = *(const uint4*)rp;
        uint4 a1 = *(const uint4*)(rp + 8);
        u32 wa[8] = {a0.x, a0.y, a0.z, a0.w, a1.x, a1.y, a1.z, a1.w};
#pragma unroll
        for (int j = 0; j < 8; ++j) {
          acc[2 * j] += __builtin_bit_cast(float, wa[j] << 16);
          acc[2 * j + 1] += __builtin_bit_cast(float, wa[j] & 0xffff0000u);
        }
      }
    }
  }

  // reduce across the 4 slots (lane bits 4,5)
#pragma unroll
  for (int i = 0; i < FR; ++i) {
    acc[i] += __shfl_xor(acc[i], 16, 64);
    acc[i] += __shfl_xor(acc[i], 32, 64);
  }

  if (slot == 0) {
    float iv = invc[node];
    float v[FR];
#pragma unroll
    for (int i = 0; i < FR; ++i) v[i] = acc[i] * iv;
    if (MODE == 1) {
      const uint4* rr = (const uint4*)(Radd + (size_t)node * D + lsub * FR);
      uint4 va = rr[0];
      u32 wa[4] = {va.x, va.y, va.z, va.w};
#pragma unroll
      for (int j = 0; j < 4; ++j) {
        v[2 * j] += __builtin_bit_cast(float, wa[j] << 16);
        v[2 * j + 1] += __builtin_bit_cast(float, wa[j] & 0xffff0000u);
      }
    }
    u32 wpk[FR / 2];
#pragma unroll
    for (int i = 0; i < FR / 2; ++i)
      wpk[i] = (u32)f2bf(v[2 * i]) | ((u32)f2bf(v[2 * i + 1]) << 16);
    uint4* o = (uint4*)(outp + (size_t)node * D + lsub * FR);
    o[0] = make_uint4(wpk[0], wpk[1], wpk[2], wpk[3]);
    if (FR == 16) o[1] = make_uint4(wpk[4], wpk[5], wpk[6], wpk[7]);
  }
}

// ---------------- bf16 MFMA GEMM:  out = epilogue(A1@W1^T + A2@W2^T) ----------------
// EPI 0: +bias relu -> bf16 out1.          EPI 1: +bias relu -> bf16 out1 AND fp8 out2.
// EPI 2: col<128 bf16 out1 | col>=128 +bias bf16 out2.
// EPI 3: col<128 fp8 out1  | col>=128 +bias bf16 out2.
template <int OUTW, int EPI>
__global__ __launch_bounds__(256) void k_gemm(const u16* __restrict__ A1, const u16* __restrict__ W1, int K1,
                                              const u16* __restrict__ A2, const u16* __restrict__ W2, int K2,
                                              const float* __restrict__ bias,
                                              void* __restrict__ out1, void* __restrict__ out2, int M) {
  __shared__ u16 lsA[128 * 64];
  __shared__ u16 lsB[128 * 64];
  const int tid = threadIdx.x, lane = tid & 63, wv = tid >> 6;
  const int wm = wv >> 1, wn = wv & 1;
  const int row0 = blockIdx.x * 128, col0 = blockIdx.y * 128;

  floatx4 acc[4][4];
#pragma unroll
  for (int r = 0; r < 4; ++r)
#pragma unroll
    for (int c = 0; c < 4; ++c) acc[r][c] = 0.f;

  for (int seg = 0; seg < 2; ++seg) {
    const u16* A = seg ? A2 : A1;
    const u16* Wm = seg ? W2 : W1;
    const int K = seg ? K2 : K1;
    if (K == 0) continue;
    for (int k0 = 0; k0 < K; k0 += 64) {
      __syncthreads();
#pragma unroll
      for (int i = 0; i < 4; ++i) {
        int chunk = i * 256 + tid;
        int r = chunk >> 3;
        int kc = chunk & 7;
        int kcs = kc ^ (r & 7);        // pre-swizzle SOURCE, linear LDS dest
        int grow = row0 + r;
        grow = grow < M ? grow : M - 1;
        gld16(A + (size_t)grow * K + (k0 + kcs * 8), lsA + (size_t)(i * 256 + wv * 64) * 8);
        int wr = col0 + r;
        gld16(Wm + (size_t)wr * K + (k0 + kcs * 8), lsB + (size_t)(i * 256 + wv * 64) * 8);
      }
      __syncthreads();
#pragma unroll
      for (int kk = 0; kk < 2; ++kk) {
        bf16x8 af[4], bb[4];
        int kc = kk * 4 + (lane >> 4);
#pragma unroll
        for (int r = 0; r < 4; ++r) {
          int row = wm * 64 + r * 16 + (lane & 15);
          af[r] = __builtin_bit_cast(bf16x8, *(const short8*)(lsA + row * 64 + ((kc ^ (row & 7)) << 3)));
        }
#pragma unroll
        for (int c = 0; c < 4; ++c) {
          int row = wn * 64 + c * 16 + (lane & 15);
          bb[c] = __builtin_bit_cast(bf16x8, *(const short8*)(lsB + row * 64 + ((kc ^ (row & 7)) << 3)));
        }
#pragma unroll
        for (int r = 0; r < 4; ++r)
#pragma unroll
          for (int c = 0; c < 4; ++c)
            acc[r][c] = __builtin_amdgcn_mfma_f32_16x16x32_bf16(af[r], bb[c], acc[r][c], 0, 0, 0);
      }
    }
  }

#pragma unroll
  for (int r = 0; r < 4; ++r) {
    int rowb = row0 + wm * 64 + r * 16 + ((lane >> 4) << 2);
#pragma unroll
    for (int c = 0; c < 4; ++c) {
      int col = col0 + wn * 64 + c * 16 + (lane & 15);
#pragma unroll
      for (int j = 0; j < 4; ++j) {
        int gr = rowb + j;
        if (gr < M) {
          float v = acc[r][c][j];
          if constexpr (EPI == 0 || EPI == 1) {
            v += bias[col];
            v = v > 0.f ? v : 0.f;
            ((u16*)out1)[(size_t)gr * OUTW + col] = f2bf(v);
            if constexpr (EPI == 1)
              ((u8*)out2)[(size_t)gr * OUTW + col] = (u8)(fp8pk_lo(v, v, 0) & 0xff);
          } else if constexpr (EPI == 2) {
            if (col < 128) {
              ((u16*)out1)[(size_t)gr * 128 + col] = f2bf(v);
            } else {
              v += bias[col - 128];
              ((u16*)out2)[(size_t)gr * 128 + (col - 128)] = f2bf(v);
            }
          } else {  // EPI == 3
            if (col < 128) {
              ((u8*)out1)[(size_t)gr * 128 + col] = (u8)(fp8pk_lo(v, v, 0) & 0xff);
            } else {
              v += bias[col - 128];
              ((u16*)out2)[(size_t)gr * 128 + (col - 128)] = f2bf(v);
            }
          }
        }
      }
    }
  }
}

// ---------------- global mean pool, phase 1: run-length partial sums (bf16 in) ----------------
__global__ __launch_bounds__(256) void k_pool_part(const u16* __restrict__ h3,
                                                   const int* __restrict__ batch,
                                                   float* __restrict__ gsum) {
  __shared__ int sb[64];
  int t = threadIdx.x;
  int n0 = blockIdx.x * 64;
  if (t < 64) sb[t] = batch[n0 + t];
  __syncthreads();
  int col = t & 127, sub = t >> 7;
  float acc = 0.f;
  int curg = -1;
  for (int i = sub; i < 64; i += 2) {
    int g = sb[i];
    if (g != curg) {
      if (curg >= 0) atomicAdd(&gsum[curg * 128 + col], acc);
      curg = g;
      acc = 0.f;
    }
    acc += bf2f(h3[(size_t)(n0 + i) * 128 + col]);
  }
  if (curg >= 0) atomicAdd(&gsum[curg * 128 + col], acc);
}

// ---------------- per-graph tail: mean finalize + v-proj chain + LayerNorm ----------------
__global__ __launch_bounds__(256) void k_tail(const float* __restrict__ gsum, const int* __restrict__ gstart,
                                              const float* __restrict__ Wv,
                                              const float* __restrict__ bv, const float* __restrict__ ipw,
                                              const float* __restrict__ ipb, const float* __restrict__ outw,
                                              const float* __restrict__ outb, const float* __restrict__ lng,
                                              const float* __restrict__ lnb, float* __restrict__ dout,
                                              float* __restrict__ eout) {
  __shared__ float sa[256], sb[256];
  __shared__ float s_mu, s_var;
  int b = blockIdx.x, t = threadIdx.x;
  if (t < 128) {
    int cg = gstart[b + 1] - gstart[b];
    float mean = gsum[b * 128 + t] / (float)(cg > 1 ? cg : 1);
    sa[t] = mean;
    dout[b * 128 + t] = mean;   // output 0: graph_vec
  }
  __syncthreads();
  float val = bv[t];
  for (int k = 0; k < 128; ++k) val += sa[k] * Wv[t * 128 + k];
  sb[t] = val;
  __syncthreads();
  float vv = ipb[512 + t];
  for (int k = 0; k < 256; ++k) vv += sb[k] * ipw[(size_t)(512 + t) * 256 + k];
  sa[t] = vv;
  __syncthreads();
  float at = outb[t];
  for (int k = 0; k < 256; ++k) at += sa[k] * outw[t * 256 + k];
  sb[t] = at;
  __syncthreads();
  for (int off = 128; off > 0; off >>= 1) {
    if (t < off) sb[t] += sb[t + off];
    __syncthreads();
  }
  if (t == 0) s_mu = sb[0] * (1.0f / 256.0f);
  __syncthreads();
  float d = at - s_mu;
  sb[t] = d * d;
  __syncthreads();
  for (int off = 128; off > 0; off >>= 1) {
    if (t < off) sb[t] += sb[t + off];
    __syncthreads();
  }
  if (t == 0) s_var = sb[0] * (1.0f / 256.0f);
  __syncthreads();
  float r = 1.0f / sqrtf(s_var + 1e-5f);
  eout[(size_t)b * 256 + t] = d * r * lng[t] + lnb[t];
}

// ---------------- broadcast per-graph embedding to nodes ----------------
__global__ void k_scat_out(const float* __restrict__ eb, const int* __restrict__ batch,
                           float* __restrict__ dout) {
  int i = blockIdx.x * 256 + threadIdx.x;
  int n = i >> 6, q = i & 63;
  float4 v = ((const float4*)eb)[(size_t)batch[n] * 64 + q];
  ((float4*)(dout + NGRAPH * 128))[i] = v;
}

// ---------------- launch ----------------
extern "C" void kernel_launch(void* const* d_in, const int* in_sizes, int n_in,
                              void* d_out, int out_size, void* d_ws, size_t ws_size,
                              hipStream_t stream) {
  (void)in_sizes; (void)n_in; (void)out_size;
  const float* x_bb = (const float*)d_in[0];
  const float* W1l = (const float*)d_in[2];
  const float* b1l = (const float*)d_in[3];
  const float* W1r = (const float*)d_in[4];
  const float* W2l = (const float*)d_in[5];
  const float* b2l = (const float*)d_in[6];
  const float* W2r = (const float*)d_in[7];
  const float* W3l = (const float*)d_in[8];
  const float* b3l = (const float*)d_in[9];
  const float* W3r = (const float*)d_in[10];
  const float* Wv = (const float*)d_in[15];
  const float* bv = (const float*)d_in[16];
  const float* ipw = (const float*)d_in[17];
  const float* ipb = (const float*)d_in[18];
  const float* outw = (const float*)d_in[19];
  const float* outb = (const float*)d_in[20];
  const float* lng = (const float*)d_in[21];
  const float* lnb = (const float*)d_in[22];
  const int* ei = (const int*)d_in[23];
  const int* batch = (const int*)d_in[24];
  float* dout = (float*)d_out;
  char* ws = (char*)d_ws;

  constexpr size_t O_W1L = 0;
  constexpr size_t O_W1R = O_W1L + 256 * 128 * 2;
  constexpr size_t O_W2L = O_W1R + 256 * 128 * 2;
  constexpr size_t O_W2R = O_W2L + 256 * 256 * 2;
  constexpr size_t O_W3L = O_W2R + 256 * 256 * 2;   // stacked [W3l;W3r] contiguous
  constexpr size_t O_W3R = O_W3L + 128 * 256 * 2;
  constexpr size_t O_XB = O_W3R + 128 * 256 * 2;                      // bf16 [N,128] xb (fallback: -> Pb)
  constexpr size_t O_MEAN1 = O_XB + (size_t)N_NODES * 128 * 2;       // bf16 [N,128] mean1 -> Rb
  constexpr size_t O_H1 = O_MEAN1 + (size_t)N_NODES * 128 * 2;       // bf16 [N,256]
  constexpr size_t O_MEAN2 = O_H1 + (size_t)N_NODES * 256 * 2;       // bf16 [N,256] mean2 -> h3b
  constexpr size_t O_H2 = O_MEAN2 + (size_t)N_NODES * 256 * 2;       // bf16 [N,256]
  constexpr size_t O_E = O_H2 + (size_t)N_NODES * 256 * 2;           // f32 [64,256]
  constexpr size_t O_CNT = O_E + 64 * 256 * 4;                       // cnt | cursor | gsum (zeroed together)
  constexpr size_t O_CUR = O_CNT + (size_t)N_NODES * 4;
  constexpr size_t O_GSUM = O_CUR + (size_t)N_NODES * 4;             // f32 [64,128]
  constexpr size_t O_RP = O_GSUM + 64 * 128 * 4;
  constexpr size_t O_INVC = O_RP + (size_t)(N_NODES + 64) * 4;
  constexpr size_t O_BSUM = O_INVC + (size_t)N_NODES * 4;
  constexpr size_t O_GST = O_BSUM + 1024;
  constexpr size_t O_PERM = O_GST + 512;
  constexpr size_t O_XQ = O_PERM + (size_t)N_EDGES * 4;              // fp8 [N,128]: xq then Pq
  constexpr size_t O_H1Q = O_XQ + (size_t)N_NODES * 128;             // fp8 [N,256]
  constexpr size_t NEED_FP8 = O_H1Q + (size_t)N_NODES * 256;

  u16* w1l = (u16*)(ws + O_W1L);  u16* w1r = (u16*)(ws + O_W1R);
  u16* w2l = (u16*)(ws + O_W2L);  u16* w2r = (u16*)(ws + O_W2R);
  u16* w3s = (u16*)(ws + O_W3L);  u16* w3r = (u16*)(ws + O_W3R);
  u16* xb = (u16*)(ws + O_XB);
  u16* mean1 = (u16*)(ws + O_MEAN1);
  u16* h1 = (u16*)(ws + O_H1);
  u16* mean2 = (u16*)(ws + O_MEAN2);
  u16* h2 = (u16*)(ws + O_H2);
  u16* Pb = (u16*)(ws + O_XB);       // fallback: bf16 P reuses xb region
  u16* Rb = (u16*)(ws + O_MEAN1);    // Rb reuses mean1 region
  u16* h3b = (u16*)(ws + O_MEAN2);   // h3 reuses mean2 region
  float* eb = (float*)(ws + O_E);
  int* cnt = (int*)(ws + O_CNT);
  int* cursor = (int*)(ws + O_CUR);
  float* gsum = (float*)(ws + O_GSUM);
  int* rowptr = (int*)(ws + O_RP);
  float* invc = (float*)(ws + O_INVC);
  int* bsum = (int*)(ws + O_BSUM);
  int* gstart = (int*)(ws + O_GST);
  int* perm = (int*)(ws + O_PERM);
  u8* xq = (u8*)(ws + O_XQ);         // fp8 x (then Pq)
  u8* Pq = (u8*)(ws + O_XQ);
  u8* h1q = (u8*)(ws + O_H1Q);

  const bool use_fp8 = (ws_size >= NEED_FP8);
  const int NB = (N_NODES + 255) / 256;  // 157
  dim3 blk(256);

  k_setup<<<512, blk, 0, stream>>>(x_bb, xb, use_fp8 ? xq : nullptr,
                                   W1l, w1l, W1r, w1r, W2l, w2l, W2r, w2r,
                                   W3l, w3s, W3r, w3r, cnt, batch, gstart);
  k_hist<<<N_EDGES / 256, blk, 0, stream>>>(ei, cnt);
  k_blocksum<<<NB, blk, 0, stream>>>(cnt, bsum, N_NODES);
  k_scan_small<<<1, blk, 0, stream>>>(bsum, NB);
  k_rowptr<<<NB, blk, 0, stream>>>(cnt, bsum, rowptr, invc, N_NODES, N_EDGES);
  k_scatter<<<N_EDGES / 256, blk, 0, stream>>>(ei, rowptr, cursor, perm);

  if (use_fp8) {
    // SAGE1 (fp8 gather of x)
    k_agg<128, 0, 1><<<N_NODES / 4, blk, 0, stream>>>(xq, mean1, rowptr, perm, invc, nullptr, N_NODES);
    k_gemm<256, 1><<<dim3(313, 2), blk, 0, stream>>>(mean1, w1l, 128, xb, w1r, 128, b1l, h1, h1q, N_NODES);
    // SAGE2 (fp8 gather of h1)
    k_agg<256, 0, 1><<<N_NODES / 4, blk, 0, stream>>>(h1q, mean2, rowptr, perm, invc, nullptr, N_NODES);
    k_gemm<256, 0><<<dim3(313, 2), blk, 0, stream>>>(mean2, w2l, 256, h1, w2r, 256, b2l, h2, nullptr, N_NODES);
    // SAGE3: stacked GEMM -> Pq (fp8) and Rb = h2@W3r+b3l (bf16); fused agg adds Rb
    k_gemm<128, 3><<<dim3(313, 2), blk, 0, stream>>>(h2, w3s, 256, nullptr, nullptr, 0, b3l, Pq, Rb, N_NODES);
    k_agg<128, 1, 1><<<N_NODES / 4, blk, 0, stream>>>(Pq, h3b, rowptr, perm, invc, Rb, N_NODES);
  } else {
    // bf16 fallback (R7 path)
    k_agg<128, 0, 0><<<N_NODES / 4, blk, 0, stream>>>(xb, mean1, rowptr, perm, invc, nullptr, N_NODES);
    k_gemm<256, 0><<<dim3(313, 2), blk, 0, stream>>>(mean1, w1l, 128, xb, w1r, 128, b1l, h1, nullptr, N_NODES);
    k_agg<256, 0, 0><<<N_NODES / 4, blk, 0, stream>>>(h1, mean2, rowptr, perm, invc, nullptr, N_NODES);
    k_gemm<256, 0><<<dim3(313, 2), blk, 0, stream>>>(mean2, w2l, 256, h1, w2r, 256, b2l, h2, nullptr, N_NODES);
    k_gemm<128, 2><<<dim3(313, 2), blk, 0, stream>>>(h2, w3s, 256, nullptr, nullptr, 0, b3l, Pb, Rb, N_NODES);
    k_agg<128, 1, 0><<<N_NODES / 4, blk, 0, stream>>>(Pb, h3b, rowptr, perm, invc, Rb, N_NODES);
  }

  // pool (partial sums) + per-graph tail + broadcast
  k_pool_part<<<N_NODES / 64, blk, 0, stream>>>(h3b, batch, gsum);
  k_tail<<<NGRAPH, blk, 0, stream>>>(gsum, gstart, Wv, bv, ipw, ipb, outw, outb, lng, lnb, dout, eb);
  k_scat_out<<<N_NODES * 64 / 256, blk, 0, stream>>>(eb, batch, dout);
}